// Round 1
// baseline (623.340 us; speedup 1.0000x reference)
//
#include <hip/hip_runtime.h>
#include <hip/hip_bf16.h>
#include <math.h>

#define BB 2
#define SS 2048
#define DD 2048
#define HH 16
#define DHH 128
#define MM (BB*SS)   // 4096

typedef __attribute__((ext_vector_type(8))) short bf16x8;
typedef __attribute__((ext_vector_type(4))) float f32x4;

__device__ __forceinline__ float b2f(short s) {
  union { unsigned int u; float f; } v;
  v.u = ((unsigned int)(unsigned short)s) << 16;
  return v.f;
}
__device__ __forceinline__ short f2b(float f) {
  union { float f; unsigned int u; } v; v.f = f;
  unsigned int u = v.u;
  u += 0x7fffu + ((u >> 16) & 1u);   // round-to-nearest-even
  return (short)(u >> 16);
}

// ---------------- fp32 -> bf16 convert ----------------
__global__ void cvt_f32_bf16(const float* __restrict__ in, short* __restrict__ out, int n4) {
  int i = blockIdx.x * blockDim.x + threadIdx.x;
  if (i >= n4) return;
  float4 v = ((const float4*)in)[i];
  short4 o;
  o.x = f2b(v.x); o.y = f2b(v.y); o.z = f2b(v.z); o.w = f2b(v.w);
  ((short4*)out)[i] = o;
}

// ---------------- GEMM: C[m,n] = sum_k A[m,k] * W[n,k] ----------------
// A: bf16 row-major [Mtot,K]; W: bf16 row-major [Ntot,K]
// MODE 0: write bf16 to [B,H,S,DH]  (m = b*S+s, n = h*DH+d)
// MODE 1: write fp32 to [Mtot,Ntot]
template<int MODE>
__global__ __launch_bounds__(256)
void gemm_bt(const short* __restrict__ A, const short* __restrict__ Bw,
             void* __restrict__ Cout, int K, int Ntot) {
  __shared__ __align__(16) short As[128][72];
  __shared__ __align__(16) short Bs[128][72];
  const int tid = threadIdx.x;
  const int lane = tid & 63;
  const int wave = tid >> 6;
  const int wm = wave >> 1, wn = wave & 1;
  const int quad = lane >> 4, l16 = lane & 15;
  const int bm = blockIdx.y * 128, bn = blockIdx.x * 128;

  f32x4 acc[4][4] = {};
  const int row = tid >> 1;
  const int cseg = (tid & 1) * 32;
  const short* aptr = A + (size_t)(bm + row) * K + cseg;
  const short* bptr = Bw + (size_t)(bn + row) * K + cseg;

  for (int k0 = 0; k0 < K; k0 += 64) {
    #pragma unroll
    for (int j = 0; j < 4; ++j) {
      *(int4*)&As[row][cseg + j*8] = *(const int4*)(aptr + k0 + j*8);
      *(int4*)&Bs[row][cseg + j*8] = *(const int4*)(bptr + k0 + j*8);
    }
    __syncthreads();
    #pragma unroll
    for (int kk = 0; kk < 64; kk += 32) {
      bf16x8 af[4], bf[4];
      #pragma unroll
      for (int t = 0; t < 4; ++t)
        af[t] = *(const bf16x8*)&As[wm*64 + t*16 + l16][kk + quad*8];
      #pragma unroll
      for (int t = 0; t < 4; ++t)
        bf[t] = *(const bf16x8*)&Bs[wn*64 + t*16 + l16][kk + quad*8];
      #pragma unroll
      for (int mt = 0; mt < 4; ++mt)
        #pragma unroll
        for (int nt = 0; nt < 4; ++nt)
          acc[mt][nt] = __builtin_amdgcn_mfma_f32_16x16x32_bf16(af[mt], bf[nt], acc[mt][nt], 0, 0, 0);
    }
    __syncthreads();
  }

  #pragma unroll
  for (int mt = 0; mt < 4; ++mt) {
    #pragma unroll
    for (int nt = 0; nt < 4; ++nt) {
      #pragma unroll
      for (int r = 0; r < 4; ++r) {
        int m = bm + wm*64 + mt*16 + quad*4 + r;
        int n = bn + wn*64 + nt*16 + l16;
        float v = acc[mt][nt][r];
        if (MODE == 0) {
          int b = m >> 11, s = m & 2047;
          int h = n >> 7,  d = n & 127;
          ((short*)Cout)[(((size_t)(b*HH + h)*SS + s)*DHH) + d] = f2b(v);
        } else {
          ((float*)Cout)[(size_t)m * Ntot + n] = v;
        }
      }
    }
  }
}

// ---------------- RoPE (interleaved) on [B,H,S,DH] bf16, in place ----------------
__global__ void rope_kernel(short* __restrict__ T, const int* __restrict__ pos, int total) {
  int idx = blockIdx.x * blockDim.x + threadIdx.x;
  if (idx >= total) return;
  int g = idx & 15;                 // which 8-elem group in DH
  int rowid = idx >> 4;             // bh*S + s
  int s = rowid & (SS - 1);
  short* p = T + (size_t)rowid * DHH + g * 8;
  float fp = (float)pos[s];
  int4 raw = *(int4*)p;
  short* e = (short*)&raw;
  #pragma unroll
  for (int j = 0; j < 4; ++j) {
    int pi = g * 4 + j;             // pair index 0..63
    float fr = expf(-0.14391156831f * (float)pi);  // theta^(-pi/64)
    float ang = fp * fr;
    float sn, cs;
    sincosf(ang, &sn, &cs);
    float xe = b2f(e[2*j]), xo = b2f(e[2*j+1]);
    float oe = xe * cs - xo * sn;
    float oo = xe * sn + xo * cs;
    e[2*j]   = f2b(oe);
    e[2*j+1] = f2b(oo);
  }
  *(int4*)p = raw;
}

// ---------------- Flash attention (causal) ----------------
// Q,K,V: bf16 [B,H,S,DH]; O: bf16 [B,S,D]
__global__ __launch_bounds__(256)
void attn(const short* __restrict__ Q, const short* __restrict__ K,
          const short* __restrict__ V, short* __restrict__ O) {
  __shared__ __align__(16) short Ks[64][136];
  __shared__ __align__(16) short Vt[128][72];   // [dim][keypos]
  __shared__ __align__(16) short Pb[4][16][72];
  const int tid = threadIdx.x;
  const int lane = tid & 63, wave = tid >> 6;
  const int quad = lane >> 4, l16 = lane & 15;
  const int qt = blockIdx.x;
  const int bh = blockIdx.y;
  const int b = bh >> 4, h = bh & 15;
  const int q0 = qt * 64;

  // Q fragments for this wave's 16 query rows (A-layout)
  bf16x8 aq[4];
  const short* qp = Q + ((size_t)bh * SS + q0 + wave*16 + l16) * DHH + quad*8;
  #pragma unroll
  for (int ks = 0; ks < 4; ++ks) aq[ks] = *(const bf16x8*)(qp + ks*32);

  f32x4 o[8] = {};
  float mrow[4], lrow[4];
  #pragma unroll
  for (int r = 0; r < 4; ++r) { mrow[r] = -1e30f; lrow[r] = 0.f; }

  const int srow = tid >> 2;          // 0..63 key row
  const int scol = (tid & 3) * 32;    // dim segment
  const float scale = 0.08838834764831845f;  // 1/sqrt(128)

  for (int kt = 0; kt <= qt; ++kt) {
    const short* kp = K + ((size_t)bh * SS + kt*64 + srow) * DHH + scol;
    const short* vp = V + ((size_t)bh * SS + kt*64 + srow) * DHH + scol;
    #pragma unroll
    for (int j = 0; j < 4; ++j)
      *(int4*)&Ks[srow][scol + j*8] = *(const int4*)(kp + j*8);
    #pragma unroll
    for (int j = 0; j < 4; ++j) {
      int4 vv = *(const int4*)(vp + j*8);
      const short* sp = (const short*)&vv;
      #pragma unroll
      for (int e = 0; e < 8; ++e)
        Vt[scol + j*8 + e][srow] = sp[e];
    }
    __syncthreads();

    // scores: 16 q-rows x 64 keys
    float sv[4][4];
    #pragma unroll
    for (int nt = 0; nt < 4; ++nt) {
      f32x4 a = {0.f, 0.f, 0.f, 0.f};
      #pragma unroll
      for (int ks = 0; ks < 4; ++ks) {
        bf16x8 bk = *(const bf16x8*)&Ks[nt*16 + l16][ks*32 + quad*8];
        a = __builtin_amdgcn_mfma_f32_16x16x32_bf16(aq[ks], bk, a, 0, 0, 0);
      }
      int kcol = kt*64 + nt*16 + l16;
      #pragma unroll
      for (int r = 0; r < 4; ++r) {
        int qrow = q0 + wave*16 + quad*4 + r;
        float sc = a[r] * scale;
        sv[nt][r] = (kcol <= qrow) ? sc : -1e30f;
      }
    }

    // online softmax per query row (row = quad*4 + r, cols across 16 lanes of quad)
    #pragma unroll
    for (int r = 0; r < 4; ++r) {
      float mx = fmaxf(fmaxf(sv[0][r], sv[1][r]), fmaxf(sv[2][r], sv[3][r]));
      #pragma unroll
      for (int off = 1; off < 16; off <<= 1)
        mx = fmaxf(mx, __shfl_xor(mx, off, 64));
      float mnew = fmaxf(mrow[r], mx);
      float alpha = __expf(mrow[r] - mnew);
      float ls = 0.f;
      #pragma unroll
      for (int nt = 0; nt < 4; ++nt) {
        float pv = __expf(sv[nt][r] - mnew);
        sv[nt][r] = pv; ls += pv;
      }
      #pragma unroll
      for (int off = 1; off < 16; off <<= 1)
        ls += __shfl_xor(ls, off, 64);
      lrow[r] = lrow[r] * alpha + ls;
      mrow[r] = mnew;
      #pragma unroll
      for (int t = 0; t < 8; ++t) o[t][r] *= alpha;
    }

    // P (C-layout) -> LDS -> A-layout for PV
    #pragma unroll
    for (int nt = 0; nt < 4; ++nt)
      #pragma unroll
      for (int r = 0; r < 4; ++r)
        Pb[wave][quad*4 + r][nt*16 + l16] = f2b(sv[nt][r]);

    #pragma unroll
    for (int k2 = 0; k2 < 2; ++k2) {
      bf16x8 ap = *(const bf16x8*)&Pb[wave][l16][k2*32 + quad*8];
      #pragma unroll
      for (int t = 0; t < 8; ++t) {
        bf16x8 bv = *(const bf16x8*)&Vt[t*16 + l16][k2*32 + quad*8];
        o[t] = __builtin_amdgcn_mfma_f32_16x16x32_bf16(ap, bv, o[t], 0, 0, 0);
      }
    }
    __syncthreads();
  }

  // epilogue: O[b, q, h*128 + d] bf16
  #pragma unroll
  for (int t = 0; t < 8; ++t) {
    #pragma unroll
    for (int r = 0; r < 4; ++r) {
      int q = q0 + wave*16 + quad*4 + r;
      float v = o[t][r] / lrow[r];
      O[((size_t)(b*SS + q)) * DD + h*DHH + t*16 + l16] = f2b(v);
    }
  }
}

extern "C" void kernel_launch(void* const* d_in, const int* in_sizes, int n_in,
                              void* d_out, int out_size, void* d_ws, size_t ws_size,
                              hipStream_t stream) {
  const float* x  = (const float*)d_in[0];
  const int* pos  = (const int*)d_in[1];
  const float* Wq = (const float*)d_in[2];
  const float* Wk = (const float*)d_in[3];
  const float* Wv = (const float*)d_in[4];
  const float* Wo = (const float*)d_in[5];

  char* ws = (char*)d_ws;
  short* xb  = (short*)(ws);
  short* wqb = (short*)(ws + 16777216);
  short* wkb = (short*)(ws + 25165824);
  short* wvb = (short*)(ws + 33554432);
  short* wob = (short*)(ws + 41943040);
  short* Qb  = (short*)(ws + 50331648);
  short* Kb  = (short*)(ws + 67108864);
  short* Vb  = (short*)(ws + 83886080);
  short* Ob  = (short*)(ws + 100663296);

  int nx4 = BB*SS*DD/4;   // 2097152
  int nw4 = DD*DD/4;      // 1048576
  cvt_f32_bf16<<<nx4/256, 256, 0, stream>>>(x,  xb,  nx4);
  cvt_f32_bf16<<<nw4/256, 256, 0, stream>>>(Wq, wqb, nw4);
  cvt_f32_bf16<<<nw4/256, 256, 0, stream>>>(Wk, wkb, nw4);
  cvt_f32_bf16<<<nw4/256, 256, 0, stream>>>(Wv, wvb, nw4);
  cvt_f32_bf16<<<nw4/256, 256, 0, stream>>>(Wo, wob, nw4);

  dim3 gg(DD/128, MM/128);   // (16, 32)
  gemm_bt<0><<<gg, 256, 0, stream>>>(xb, wqb, Qb, DD, DD);
  gemm_bt<0><<<gg, 256, 0, stream>>>(xb, wkb, Kb, DD, DD);
  gemm_bt<0><<<gg, 256, 0, stream>>>(xb, wvb, Vb, DD, DD);

  int nrope = BB*HH*SS*16;   // 1048576
  rope_kernel<<<nrope/256, 256, 0, stream>>>(Qb, pos, nrope);
  rope_kernel<<<nrope/256, 256, 0, stream>>>(Kb, pos, nrope);

  dim3 ga(SS/64, BB*HH);     // (32, 32)
  attn<<<ga, 256, 0, stream>>>(Qb, Kb, Vb, Ob);

  gemm_bt<1><<<gg, 256, 0, stream>>>(Ob, wob, d_out, DD, DD);
}